// Round 12
// baseline (504.323 us; speedup 1.0000x reference)
//
#include <hip/hip_runtime.h>
#include <hip/hip_cooperative_groups.h>
#include <cstdint>
#include <cstddef>

// Problem constants
#define B_ 4
#define T_ 2048
#define C_ 1024
#define H_ 16
#define D_ 64

typedef __attribute__((ext_vector_type(8))) __bf16 bf16x8;
typedef __attribute__((ext_vector_type(4))) float floatx4;

#define QSCL (0.125f * 1.44269504088896f)  // 1/sqrt(64) * log2(e), folded into Q
#define FMAX 24.0f  // fixed softmax offset (log2 domain); scores ~N(0,0.33)

__device__ __forceinline__ unsigned short f2bf(float f) {
  union { float f; unsigned int u; } v; v.f = f;
  unsigned int r = v.u + 0x7fffu + ((v.u >> 16) & 1u);  // RNE
  return (unsigned short)(r >> 16);
}
__device__ __forceinline__ ushort4 pk4(float a, float b, float c, float d) {
  ushort4 u; u.x = f2bf(a); u.y = f2bf(b); u.z = f2bf(c); u.w = f2bf(d);
  return u;
}
__device__ __forceinline__ bf16x8 cvt8(float4 a, float4 b) {
  bf16x8 r;
  r[0] = a.x; r[1] = a.y; r[2] = a.z; r[3] = a.w;
  r[4] = b.x; r[5] = b.y; r[6] = b.z; r[7] = b.w;
  return r;
}
__device__ __forceinline__ unsigned pkbf2(float a, float b) {
  union { __bf16 h[2]; unsigned u; } w;
  w.h[0] = (__bf16)a; w.h[1] = (__bf16)b;
  return w.u;
}

// async 16B global -> LDS (dest = wave-uniform base + lane*16)
__device__ __forceinline__ void gl_lds16(const void* g, void* l) {
  __builtin_amdgcn_global_load_lds(
      (const __attribute__((address_space(1))) unsigned int*)g,
      (__attribute__((address_space(3))) unsigned int*)l, 16, 0, 0);
}

// ---------------------------------------------------------------------------
// Fused cooperative kernel.  R11 tally: ~175us of kernel time vs 245us total
// -> ~70us of inter-dispatch launch gaps.  One kernel, grid 512x256 = exactly
// 2 blocks/CU (launch_bounds(256,2); 64KB LDS union -> 128KB/CU), stages
// separated by grid.sync():
//   A: x,W_qkv fp32->bf16   B: QKV gemm (3 tiles/blk)   C: attn (paired bands)
//   D: W_out->bf16 into dead V^T                        E: out-proj (1 tile/blk)
// ---------------------------------------------------------------------------
struct GemmSM { unsigned short As[2][8192]; unsigned short Bs[2][8192]; };  // 64KB
struct AttnSM { unsigned short Ks[2][4096]; unsigned short Vs[2][4096]; };  // 32KB
union FusedSM { GemmSM g; AttnSM a; };

// 128x128 GEMM tile, both operands bf16 via global_load_lds, dbuf + 1 barrier
// per K-step, XOR source-swizzle (rule 21).  EPI/GATHER as before, WBF==1 only.
template<int EPI, int GATHER>
__device__ __forceinline__ void gemm_body_w1(
    const unsigned short* __restrict__ Abf,
    const unsigned short* __restrict__ Wb,
    const float* __restrict__ bias, float* __restrict__ out,
    unsigned short* __restrict__ qws, unsigned short* __restrict__ kws,
    unsigned short* __restrict__ vtws,
    unsigned short* As, unsigned short* Bs, int bm, int bn)
{
  const int tid  = threadIdx.x;
  const int lane = tid & 63;
  const int wid  = tid >> 6;
  const int col  = lane & 15;
  const int quad = lane >> 4;
  const int wm = (wid >> 1) << 6;
  const int wn = (wid & 1) << 6;
  const int r0 = tid >> 3;
  const int c0 = tid & 7;

  floatx4 acc[4][4];
#pragma unroll
  for (int i = 0; i < 4; ++i)
#pragma unroll
    for (int j = 0; j < 4; ++j)
      acc[i][j] = (floatx4){0.f, 0.f, 0.f, 0.f};

  auto stage = [&](int k0, int nb) {
#pragma unroll
    for (int s = 0; s < 4; ++s) {
      const int row  = (s << 5) + r0;
      const int colE = ((c0 ^ (row & 7)) << 3);
      const unsigned short* gsrc;
      if (GATHER) {
        const int m = bm + row;
        const int b = m >> 11, t = m & 2047;
        const int hh = k0 >> 6;
        gsrc = Abf + ((((size_t)(b * 16 + hh) << 11) + t) << 6) + colE;
      } else {
        gsrc = Abf + (size_t)(bm + row) * 1024 + k0 + colE;
      }
      gl_lds16(gsrc, (char*)As + nb * 16384 + (s << 12) + (wid << 10));
      gl_lds16(Wb + (size_t)(bn + row) * 1024 + k0 + colE,
               (char*)Bs + nb * 16384 + (s << 12) + (wid << 10));
    }
  };

  stage(0, 0);
  __syncthreads();

  for (int kt = 0; kt < 16; ++kt) {
    const int buf = kt & 1;
    if (kt + 1 < 16) stage((kt + 1) << 6, buf ^ 1);
#pragma unroll
    for (int kk = 0; kk < 64; kk += 32) {
      bf16x8 af[4], bfr[4];
#pragma unroll
      for (int i = 0; i < 4; ++i) {
        const int r = wm + i * 16 + col;
        af[i] = *(const bf16x8*)&As[buf * 8192 + (r << 6) + ((kk + quad * 8) ^ ((r & 7) << 3))];
      }
#pragma unroll
      for (int j = 0; j < 4; ++j) {
        const int r = wn + j * 16 + col;
        bfr[j] = *(const bf16x8*)&Bs[buf * 8192 + (r << 6) + ((kk + quad * 8) ^ ((r & 7) << 3))];
      }
#pragma unroll
      for (int i = 0; i < 4; ++i)
#pragma unroll
        for (int j = 0; j < 4; ++j)
          acc[i][j] = __builtin_amdgcn_mfma_f32_16x16x32_bf16(af[i], bfr[j], acc[i][j], 0, 0, 0);
    }
    __syncthreads();
  }

  // Epilogue.  C/D layout: row = quad*4 + r, col = lane&15 (m89/m91).
#pragma unroll
  for (int i = 0; i < 4; ++i) {
    const int row = bm + wm + i * 16 + quad * 4;
#pragma unroll
    for (int j = 0; j < 4; ++j) {
      const int n  = bn + wn + j * 16 + col;
      const float bv = bias[n];
      float v[4];
#pragma unroll
      for (int r = 0; r < 4; ++r) v[r] = acc[i][j][r] + bv;

      if (EPI == 1) {
#pragma unroll
        for (int r = 0; r < 4; ++r)
          out[(size_t)(row + r) * 1024 + n] = v[r];
      } else {
        const int s   = n >> 10;
        const int rem = n & 1023;
        const int h   = rem >> 6;
        const int d   = rem & 63;
        const int b   = row >> 11;
        const int t   = row & 2047;
        const size_t bh = (size_t)(b * H_ + h);
        if (s == 0) {
#pragma unroll
          for (int r = 0; r < 4; ++r)
            qws[(bh * T_ + t + r) * D_ + d] = f2bf(v[r] * QSCL);
        } else if (s == 1) {
#pragma unroll
          for (int r = 0; r < 4; ++r)
            kws[(bh * T_ + t + r) * D_ + d] = f2bf(v[r]);
        } else {
          *(ushort4*)&vtws[(bh * D_ + d) * T_ + t] = pk4(v[0], v[1], v[2], v[3]);
        }
      }
    }
  }
}

__global__ __launch_bounds__(256, 2)
void fused_all(const float* __restrict__ x,
               const float* __restrict__ Wq,
               const float* __restrict__ bqv,
               const float* __restrict__ Wo,
               const float* __restrict__ bov,
               float* __restrict__ out,
               unsigned short* __restrict__ qws,
               unsigned short* __restrict__ vtws,
               unsigned short* __restrict__ kws,
               unsigned short* __restrict__ xbf,
               unsigned short* __restrict__ wqbf)
{
  __shared__ FusedSM sm;
  cooperative_groups::grid_group grid = cooperative_groups::this_grid();
  const int tid  = threadIdx.x;
  const int lane = tid & 63;
  const int wid  = tid >> 6;
  const int col  = lane & 15;
  const int quad = lane >> 4;

  // ---- stage A: x -> xbf, W_qkv -> wqbf ----
  {
    const int n1 = 1048576;   // per/8
    const int n2 = 393216;    // 3*C*C/8
    for (int i = (int)blockIdx.x * 256 + tid; i < n1 + n2; i += 512 * 256) {
      if (i < n1) {
        const float4* s = (const float4*)x + 2 * (size_t)i;
        ((bf16x8*)xbf)[i] = cvt8(s[0], s[1]);
      } else {
        const int j = i - n1;
        const float4* s = (const float4*)Wq + 2 * (size_t)j;
        ((bf16x8*)wqbf)[j] = cvt8(s[0], s[1]);
      }
    }
  }
  grid.sync();

  // ---- stage B: QKV projection, 1536 tiles = 3 per block ----
  for (int t5 = 0; t5 < 3; ++t5) {
    const int tile = (int)blockIdx.x + (t5 << 9);
    const int by = tile / 24, bx = tile - by * 24;
    gemm_body_w1<0, 0>(xbf, wqbf, bqv, nullptr, qws, kws, vtws,
                       &sm.g.As[0][0], &sm.g.Bs[0][0], by << 7, bx << 7);
  }
  grid.sync();

  // ---- stage C: causal flash attention (v7 body, paired bands -> uniform 34
  //      tiles/block; 512 blocks = exactly resident) ----
  {
    unsigned short* Kls = &sm.a.Ks[0][0];
    unsigned short* Vls = &sm.a.Vs[0][0];
    const int bh = (int)blockIdx.x & 63;
    const int p  = (int)blockIdx.x >> 6;   // 0..7
    const unsigned short* Kp  = kws + (size_t)bh * T_ * D_;
    const unsigned short* Vtp = vtws + (size_t)bh * D_ * T_;

    bf16x8 vones;
#pragma unroll
    for (int i = 0; i < 8; ++i) vones[i] = (__bf16)1.0f;

    const int srow8 = lane >> 3;
    const int aswz  = ((lane & 7) ^ srow8) << 3;
    auto astage = [&](int kt_, int b_) {
#pragma unroll
      for (int c2 = 0; c2 < 2; ++c2) {
        const int cb = wid + (c2 << 2);
        gl_lds16(Kp + ((size_t)((kt_ << 6) + (cb << 3) + srow8) << 6) + aswz,
                 (char*)Kls + b_ * 8192 + (cb << 10));
        gl_lds16(Vtp + ((size_t)((cb << 3) + srow8) << 11) + (kt_ << 6) + aswz,
                 (char*)Vls + b_ * 8192 + (cb << 10));
      }
    };

    for (int half = 0; half < 2; ++half) {
      const int band = half ? (15 - p) : p;   // pair (p, 15-p): uniform work
      const int nk   = (band << 1) + 2;
      const int q0   = (band << 7) + (wid << 5);
      unsigned short* Qp = qws + ((size_t)bh * T_ + q0) * D_;

      bf16x8 bq[2][2];
#pragma unroll
      for (int h = 0; h < 2; ++h) {
        bq[h][0] = *(const bf16x8*)&Qp[(h * 16 + col) * D_ + quad * 8];
        bq[h][1] = *(const bf16x8*)&Qp[(h * 16 + col) * D_ + 32 + quad * 8];
      }

      floatx4 o[2][4], ol[2];
#pragma unroll
      for (int h = 0; h < 2; ++h) {
        ol[h] = (floatx4){0.f, 0.f, 0.f, 0.f};
#pragma unroll
        for (int j = 0; j < 4; ++j) o[h][j] = (floatx4){0.f, 0.f, 0.f, 0.f};
      }

      astage(0, 0);
      __syncthreads();

      for (int kt = 0; kt < nk; ++kt) {
        const int buf = kt & 1;
        if (kt + 1 < nk) astage(kt + 1, buf ^ 1);

        const unsigned short* Kb = Kls + buf * 4096;
        bf16x8 kA[4], kB[4];
#pragma unroll
        for (int g = 0; g < 4; ++g) {
          const int r = g * 16 + col;
          kA[g] = *(const bf16x8*)&Kb[(r << 6) + ((quad ^ (col & 7)) << 3)];
          kB[g] = *(const bf16x8*)&Kb[(r << 6) + (((quad | 4) ^ (col & 7)) << 3)];
        }

        floatx4 s[2][4];
        __builtin_amdgcn_s_setprio(1);
#pragma unroll
        for (int h = 0; h < 2; ++h)
#pragma unroll
          for (int g = 0; g < 4; ++g) {
            s[h][g] = (floatx4){-FMAX, -FMAX, -FMAX, -FMAX};
            s[h][g] = __builtin_amdgcn_mfma_f32_16x16x32_bf16(kA[g], bq[h][0], s[h][g], 0, 0, 0);
            s[h][g] = __builtin_amdgcn_mfma_f32_16x16x32_bf16(kB[g], bq[h][1], s[h][g], 0, 0, 0);
          }
        __builtin_amdgcn_s_setprio(0);

        const unsigned short* Vb = Vls + buf * 4096;
        bf16x8 vA[4], vB[4];
#pragma unroll
        for (int j = 0; j < 4; ++j) {
          const int r = j * 16 + col;
          vA[j] = *(const bf16x8*)&Vb[(r << 6) + ((quad ^ (col & 7)) << 3)];
          vB[j] = *(const bf16x8*)&Vb[(r << 6) + (((quad | 4) ^ (col & 7)) << 3)];
        }

        if (kt >= nk - 2) {
#pragma unroll
          for (int h = 0; h < 2; ++h) {
            const int lim = q0 - (kt << 6) + (h << 4) + col;
#pragma unroll
            for (int g = 0; g < 4; ++g)
#pragma unroll
              for (int r = 0; r < 4; ++r)
                if (g * 16 + quad * 4 + r > lim) s[h][g][r] = -1e30f;
          }
        }

#pragma unroll
        for (int h = 0; h < 2; ++h)
#pragma unroll
          for (int g = 0; g < 4; ++g)
#pragma unroll
            for (int r = 0; r < 4; ++r)
              s[h][g][r] = __builtin_amdgcn_exp2f(s[h][g][r]);

        __builtin_amdgcn_s_setprio(1);
#pragma unroll
        for (int h = 0; h < 2; ++h) {
          unsigned dw[4][2];
#pragma unroll
          for (int g = 0; g < 4; ++g) {
            dw[g][0] = pkbf2(s[h][g][0], s[h][g][1]);
            dw[g][1] = pkbf2(s[h][g][2], s[h][g][3]);
          }
          unsigned aw[4], bw[4];
          {
            auto t = __builtin_amdgcn_permlane32_swap(dw[0][0], dw[1][0], false, false);
            auto u = __builtin_amdgcn_permlane16_swap(t[0], t[1], false, false);
            aw[0] = u[0]; aw[2] = u[1];
          }
          {
            auto t = __builtin_amdgcn_permlane32_swap(dw[0][1], dw[1][1], false, false);
            auto u = __builtin_amdgcn_permlane16_swap(t[0], t[1], false, false);
            aw[1] = u[0]; aw[3] = u[1];
          }
          {
            auto t = __builtin_amdgcn_permlane32_swap(dw[2][0], dw[3][0], false, false);
            auto u = __builtin_amdgcn_permlane16_swap(t[0], t[1], false, false);
            bw[0] = u[0]; bw[2] = u[1];
          }
          {
            auto t = __builtin_amdgcn_permlane32_swap(dw[2][1], dw[3][1], false, false);
            auto u = __builtin_amdgcn_permlane16_swap(t[0], t[1], false, false);
            bw[1] = u[0]; bw[3] = u[1];
          }
          union { unsigned u[4]; bf16x8 v; } pa0, pa1;
#pragma unroll
          for (int w = 0; w < 4; ++w) { pa0.u[w] = aw[w]; pa1.u[w] = bw[w]; }

#pragma unroll
          for (int j = 0; j < 4; ++j) {
            o[h][j] = __builtin_amdgcn_mfma_f32_16x16x32_bf16(pa0.v, vA[j], o[h][j], 0, 0, 0);
            o[h][j] = __builtin_amdgcn_mfma_f32_16x16x32_bf16(pa1.v, vB[j], o[h][j], 0, 0, 0);
          }
          ol[h] = __builtin_amdgcn_mfma_f32_16x16x32_bf16(pa0.v, vones, ol[h], 0, 0, 0);
          ol[h] = __builtin_amdgcn_mfma_f32_16x16x32_bf16(pa1.v, vones, ol[h], 0, 0, 0);
        }
        __builtin_amdgcn_s_setprio(0);

        __syncthreads();
      }

#pragma unroll
      for (int h = 0; h < 2; ++h) {
        float lr[4];
#pragma unroll
        for (int r = 0; r < 4; ++r) lr[r] = 1.0f / ol[h][r];
#pragma unroll
        for (int j = 0; j < 4; ++j)
#pragma unroll
          for (int r = 0; r < 4; ++r)
            Qp[(size_t)(h * 16 + quad * 4 + r) * D_ + j * 16 + col] =
                f2bf(o[h][j][r] * lr[r]);
      }
    }
  }
  grid.sync();

  // ---- stage D: W_out -> bf16 into dead V^T region ----
  {
    for (int i = (int)blockIdx.x * 256 + tid; i < 131072; i += 512 * 256) {
      const float4* s = (const float4*)Wo + 2 * (size_t)i;
      ((bf16x8*)vtws)[i] = cvt8(s[0], s[1]);
    }
  }
  grid.sync();

  // ---- stage E: out-projection, 512 tiles = 1 per block ----
  {
    const int tile = (int)blockIdx.x;
    const int by = tile >> 3, bx = tile & 7;
    gemm_body_w1<1, 1>(qws, vtws, bov, out, nullptr, nullptr, nullptr,
                       &sm.g.As[0][0], &sm.g.Bs[0][0], by << 7, bx << 7);
  }
}

// ---------------------------------------------------------------------------
// Fallback multi-dispatch path (R11 kernels, unchanged).
// ---------------------------------------------------------------------------
__global__ __launch_bounds__(256)
void conv_bf16(const float* __restrict__ src, unsigned short* __restrict__ dst,
               int n8) {
  for (int i = blockIdx.x * 256 + threadIdx.x; i < n8; i += gridDim.x * 256) {
    const float4* s = (const float4*)src + 2 * (size_t)i;
    float4 a = s[0], b = s[1];
    ((bf16x8*)dst)[i] = cvt8(a, b);
  }
}

__global__ __launch_bounds__(256)
void conv_tri(const float* __restrict__ s1, unsigned short* __restrict__ d1, int n1,
              const float* __restrict__ s2, unsigned short* __restrict__ d2, int n2,
              const float* __restrict__ s3, unsigned short* __restrict__ d3, int n3) {
  for (int i = blockIdx.x * 256 + threadIdx.x; i < n1 + n2 + n3; i += gridDim.x * 256) {
    const float4* sp; bf16x8* dp;
    if (i < n1)           { sp = (const float4*)s1 + 2 * (size_t)i;       dp = (bf16x8*)d1 + i; }
    else if (i < n1 + n2) { int j = i - n1;      sp = (const float4*)s2 + 2 * (size_t)j; dp = (bf16x8*)d2 + j; }
    else                  { int j = i - n1 - n2; sp = (const float4*)s3 + 2 * (size_t)j; dp = (bf16x8*)d3 + j; }
    float4 a = sp[0], b = sp[1];
    *dp = cvt8(a, b);
  }
}

template<int EPI, int GATHER, int WBF>
__global__ __launch_bounds__(256, 2)
void gemm_bt(const unsigned short* __restrict__ Abf,
             const void* __restrict__ Wraw,
             const float* __restrict__ bias,
             float* __restrict__ out,
             unsigned short* __restrict__ qws,
             unsigned short* __restrict__ kws,
             unsigned short* __restrict__ vtws)
{
  alignas(16) __shared__ unsigned short As[2][128 * 64];
  alignas(16) __shared__ unsigned short Bs[2][WBF ? 128 * 64 : 128 * 72];
  const int tid  = threadIdx.x;
  const int lane = tid & 63;
  const int wid  = tid >> 6;
  const int col  = lane & 15;
  const int quad = lane >> 4;
  const int wm = (wid >> 1) << 6;
  const int wn = (wid & 1) << 6;
  const int bm = blockIdx.y << 7;
  const int bn = blockIdx.x << 7;

  const float* Wf          = (const float*)Wraw;
  const unsigned short* Wb = (const unsigned short*)Wraw;

  const int r0 = tid >> 3;
  const int c0 = tid & 7;

  floatx4 acc[4][4];
#pragma unroll
  for (int i = 0; i < 4; ++i)
#pragma unroll
    for (int j = 0; j < 4; ++j)
      acc[i][j] = (floatx4){0.f, 0.f, 0.f, 0.f};

#define GSTAGE(k0_, nb_)                                                      \
  do {                                                                        \
    _Pragma("unroll") for (int s = 0; s < 4; ++s) {                           \
      const int row  = (s << 5) + r0;                                         \
      const int colE = ((c0 ^ (row & 7)) << 3);                               \
      const unsigned short* gsrc;                                             \
      if (GATHER) {                                                           \
        const int m = bm + row;                                               \
        const int b = m >> 11, t = m & 2047;                                  \
        const int hh = (k0_) >> 6;                                            \
        gsrc = Abf + ((((size_t)(b * 16 + hh) << 11) + t) << 6) + colE;       \
      } else {                                                                \
        gsrc = Abf + (size_t)(bm + row) * 1024 + (k0_) + colE;                \
      }                                                                       \
      gl_lds16(gsrc, (char*)&As[nb_][0] + (s << 12) + (wid << 10));           \
      if (WBF) {                                                              \
        const unsigned short* ws2 = Wb + (size_t)(bn + row) * 1024 + (k0_) + colE; \
        gl_lds16(ws2, (char*)&Bs[nb_][0] + (s << 12) + (wid << 10));          \
      } else {                                                                \
        const int kc = c0 << 3;                                               \
        const float* wsrc = &Wf[(size_t)(bn + row) * 1024 + (k0_) + kc];      \
        float4 w0 = *(const float4*)wsrc;                                     \
        float4 w1 = *(const float4*)(wsrc + 4);                               \
        *(bf16x8*)&Bs[nb_][row * 72 + kc] = cvt8(w0, w1);                     \
      }                                                                       \
    }                                                                         \
  } while (0)

  GSTAGE(0, 0);
  __syncthreads();

  for (int kt = 0; kt < 16; ++kt) {
    const int buf = kt & 1;
    if (kt + 1 < 16) GSTAGE((kt + 1) << 6, buf ^ 1);

#pragma unroll
    for (int kk = 0; kk < 64; kk += 32) {
      bf16x8 af[4], bfr[4];
#pragma unroll
      for (int i = 0; i < 4; ++i) {
        const int r = wm + i * 16 + col;
        af[i] = *(const bf16x8*)&As[buf][(r << 6) + ((kk + quad * 8) ^ ((r & 7) << 3))];
      }
#pragma unroll
      for (int j = 0; j < 4; ++j) {
        const int r = wn + j * 16 + col;
        if (WBF)
          bfr[j] = *(const bf16x8*)&Bs[buf][(r << 6) + ((kk + quad * 8) ^ ((r & 7) << 3))];
        else
          bfr[j] = *(const bf16x8*)&Bs[buf][r * 72 + kk + quad * 8];
      }
#pragma unroll
      for (int i = 0; i < 4; ++i)
#pragma unroll
        for (int j = 0; j < 4; ++j)
          acc[i][j] = __builtin_amdgcn_mfma_f32_16x16x32_bf16(af[i], bfr[j], acc[i][j], 0, 0, 0);
    }
    __syncthreads();
  }
#undef GSTAGE

#pragma unroll
  for (int i = 0; i < 4; ++i) {
    const int row = bm + wm + i * 16 + quad * 4;
#pragma unroll
    for (int j = 0; j < 4; ++j) {
      const int n  = bn + wn + j * 16 + col;
      const float bv = bias[n];
      float v[4];
#pragma unroll
      for (int r = 0; r < 4; ++r) v[r] = acc[i][j][r] + bv;

      if (EPI == 1) {
#pragma unroll
        for (int r = 0; r < 4; ++r)
          out[(size_t)(row + r) * 1024 + n] = v[r];
      } else {
        const int s   = n >> 10;
        const int rem = n & 1023;
        const int h   = rem >> 6;
        const int d   = rem & 63;
        const int b   = row >> 11;
        const int t   = row & 2047;
        const size_t bh = (size_t)(b * H_ + h);
        if (s == 0) {
#pragma unroll
          for (int r = 0; r < 4; ++r)
            qws[(bh * T_ + t + r) * D_ + d] = f2bf(v[r] * QSCL);
        } else if (s == 1) {
#pragma unroll
          for (int r = 0; r < 4; ++r)
            kws[(bh * T_ + t + r) * D_ + d] = f2bf(v[r]);
        } else {
          *(ushort4*)&vtws[(bh * D_ + d) * T_ + t] = pk4(v[0], v[1], v[2], v[3]);
        }
      }
    }
  }
}

// Standalone attn (R11 v8) for the fallback path.
__global__ __launch_bounds__(256, 2)
void attn_causal(unsigned short* __restrict__ qws,
                 const unsigned short* __restrict__ kws,
                 const unsigned short* __restrict__ vtws)
{
  alignas(16) __shared__ unsigned short Ks[2][64 * 64];
  alignas(16) __shared__ unsigned short Vs[2][64 * 64];
  const int tid  = threadIdx.x;
  const int lane = tid & 63;
  const int wid  = tid >> 6;
  const int col  = lane & 15;
  const int quad = lane >> 4;

  const int bh   = blockIdx.x & 63;
  const int band = 7 - (blockIdx.x >> 6);

  const unsigned short* Kp  = kws + (size_t)bh * T_ * D_;
  const unsigned short* Vtp = vtws + (size_t)bh * D_ * T_;

  bf16x8 vones;
#pragma unroll
  for (int i = 0; i < 8; ++i) vones[i] = (__bf16)1.0f;

  const int srow8 = lane >> 3;
  const int swz   = ((lane & 7) ^ srow8) << 3;

#define STAGE(kt_, b_)                                                        \
  do {                                                                        \
    _Pragma("unroll") for (int c2 = 0; c2 < 2; ++c2) {                        \
      const int cb = wid + (c2 << 2);                                         \
      gl_lds16(Kp + ((size_t)(((kt_) << 6) + (cb << 3) + srow8) << 6) + swz,  \
               (char*)&Ks[b_][0] + (cb << 10));                               \
      gl_lds16(Vtp + ((size_t)((cb << 3) + srow8) << 11) + ((kt_) << 6) + swz,\
               (char*)&Vs[b_][0] + (cb << 10));                               \
    }                                                                         \
  } while (0)

  const int nk    = (band + 1) << 2;
  const int kdiag = (band << 2) + wid;
  const int q0    = (band << 8) + (wid << 6);
  unsigned short* Qp = qws + ((size_t)bh * T_ + q0) * D_;

  bf16x8 bq[4][2];
#pragma unroll
  for (int h = 0; h < 4; ++h) {
    bq[h][0] = *(const bf16x8*)&Qp[(h * 16 + col) * D_ + quad * 8];
    bq[h][1] = *(const bf16x8*)&Qp[(h * 16 + col) * D_ + 32 + quad * 8];
  }

  floatx4 o[4][4], ol[4];
#pragma unroll
  for (int h = 0; h < 4; ++h) {
    ol[h] = (floatx4){0.f, 0.f, 0.f, 0.f};
#pragma unroll
    for (int j = 0; j < 4; ++j) o[h][j] = (floatx4){0.f, 0.f, 0.f, 0.f};
  }

  STAGE(0, 0);
  __syncthreads();

  for (int kt = 0; kt < nk; ++kt) {
    const int buf = kt & 1;
    if (kt + 1 < nk) STAGE(kt + 1, buf ^ 1);

    if (kt <= kdiag) {
      const unsigned short* Kb = &Ks[buf][0];
      bf16x8 kA[4], kB[4];
#pragma unroll
      for (int g = 0; g < 4; ++g) {
        const int r = g * 16 + col;
        kA[g] = *(const bf16x8*)&Kb[(r << 6) + ((quad ^ (col & 7)) << 3)];
        kB[g] = *(const bf16x8*)&Kb[(r << 6) + (((quad | 4) ^ (col & 7)) << 3)];
      }
      const unsigned short* Vb = &Vs[buf][0];
      bf16x8 vA[4], vB[4];
#pragma unroll
      for (int j = 0; j < 4; ++j) {
        const int r = j * 16 + col;
        vA[j] = *(const bf16x8*)&Vb[(r << 6) + ((quad ^ (col & 7)) << 3)];
        vB[j] = *(const bf16x8*)&Vb[(r << 6) + (((quad | 4) ^ (col & 7)) << 3)];
      }

#pragma unroll
      for (int hp = 0; hp < 2; ++hp) {
        floatx4 s[2][4];
        __builtin_amdgcn_s_setprio(1);
#pragma unroll
        for (int hh = 0; hh < 2; ++hh) {
          const int h = hp * 2 + hh;
#pragma unroll
          for (int g = 0; g < 4; ++g) {
            s[hh][g] = (floatx4){-FMAX, -FMAX, -FMAX, -FMAX};
            s[hh][g] = __builtin_amdgcn_mfma_f32_16x16x32_bf16(kA[g], bq[h][0], s[hh][g], 0, 0, 0);
            s[hh][g] = __builtin_amdgcn_mfma_f32_16x16x32_bf16(kB[g], bq[h][1], s[hh][g], 0, 0, 0);
          }
        }
        __builtin_amdgcn_s_setprio(0);

        if (kt == kdiag) {
#pragma unroll
          for (int hh = 0; hh < 2; ++hh) {
            const int lim = ((hp * 2 + hh) << 4) + col;
#pragma unroll
            for (int g = 0; g < 4; ++g)
#pragma unroll
              for (int r = 0; r < 4; ++r)
                if (g * 16 + quad * 4 + r > lim) s[hh][g][r] = -1e30f;
          }
        }

#pragma unroll
        for (int hh = 0; hh < 2; ++hh)
#pragma unroll
          for (int g = 0; g < 4; ++g)
#pragma unroll
            for (int r = 0; r < 4; ++r)
              s[hh][g][r] = __builtin_amdgcn_exp2f(s[hh][g][r]);

        __builtin_amdgcn_s_setprio(1);
#pragma unroll
        for (int hh = 0; hh < 2; ++hh) {
          const int h = hp * 2 + hh;
          unsigned dw[4][2];
#pragma unroll
          for (int g = 0; g < 4; ++g) {
            dw[g][0] = pkbf2(s[hh][g][0], s[hh][g][1]);
            dw[g][1] = pkbf2(s[hh][g][2], s[hh][g][3]);
          }
          unsigned aw[4], bw[4];
          {
            auto t = __builtin_amdgcn_permlane32_swap(dw[0][0], dw[1][0], false, false);
            auto u = __builtin_amdgcn_permlane16_swap(t[0], t[1], false, false);
            aw[0] = u[0]; aw[2] = u[1];
          }
          {
            auto t = __builtin_amdgcn_permlane32_swap(dw[0][1], dw[1][1], false, false);
            auto u = __builtin_amdgcn_permlane16_swap(t[0], t[1], false, false);
            aw[1] = u[0]; aw[3] = u[1];
          }
          {
            auto t = __builtin_amdgcn_permlane32_swap(dw[2][0], dw[3][0], false, false);
            auto u = __builtin_amdgcn_permlane16_swap(t[0], t[1], false, false);
            bw[0] = u[0]; bw[2] = u[1];
          }
          {
            auto t = __builtin_amdgcn_permlane32_swap(dw[2][1], dw[3][1], false, false);
            auto u = __builtin_amdgcn_permlane16_swap(t[0], t[1], false, false);
            bw[1] = u[0]; bw[3] = u[1];
          }
          union { unsigned u[4]; bf16x8 v; } pa0, pa1;
#pragma unroll
          for (int w = 0; w < 4; ++w) { pa0.u[w] = aw[w]; pa1.u[w] = bw[w]; }

#pragma unroll
          for (int j = 0; j < 4; ++j) {
            o[h][j] = __builtin_amdgcn_mfma_f32_16x16x32_bf16(pa0.v, vA[j], o[h][j], 0, 0, 0);
            o[h][j] = __builtin_amdgcn_mfma_f32_16x16x32_bf16(pa1.v, vB[j], o[h][j], 0, 0, 0);
          }
          ol[h] = __builtin_amdgcn_mfma_f32_16x16x32_bf16(pa0.v, vones, ol[h], 0, 0, 0);
          ol[h] = __builtin_amdgcn_mfma_f32_16x16x32_bf16(pa1.v, vones, ol[h], 0, 0, 0);
        }
        __builtin_amdgcn_s_setprio(0);
      }
    }
    __syncthreads();
  }

#pragma unroll
  for (int h = 0; h < 4; ++h) {
    float lr[4];
#pragma unroll
    for (int r = 0; r < 4; ++r) lr[r] = 1.0f / ol[h][r];
#pragma unroll
    for (int j = 0; j < 4; ++j)
#pragma unroll
      for (int r = 0; r < 4; ++r)
        Qp[(size_t)(h * 16 + quad * 4 + r) * D_ + j * 16 + col] =
            f2bf(o[h][j][r] * lr[r]);
  }
#undef STAGE
}

extern "C" void kernel_launch(void* const* d_in, const int* in_sizes, int n_in,
                              void* d_out, int out_size, void* d_ws, size_t ws_size,
                              hipStream_t stream) {
  const float* x     = (const float*)d_in[0];  // [B,T,C] fp32
  const float* W_qkv = (const float*)d_in[2];  // [3C,C] fp32
  const float* b_qkv = (const float*)d_in[3];  // [3C]
  const float* W_out = (const float*)d_in[4];  // [C,C]
  const float* b_out = (const float*)d_in[5];  // [C]
  float* out = (float*)d_out;                  // [B,T,C] fp32 (32 MB)

  // Memory plan (needs only bigws = 38 MB, confirmed active since R5):
  //   qws (Q/ctx) d_ws+0 | vtws (V^T, then W_out bf16) d_ws+16M |
  //   kws (K) d_out+0 | xbf (x bf16) d_out+16M | wqbf d_ws+32M (6MB)
  const size_t per = (size_t)B_ * H_ * T_ * D_;  // 8M elements
  unsigned short* qws  = (unsigned short*)d_ws;
  unsigned short* vtws = qws + per;
  unsigned short* kws  = (unsigned short*)d_out;
  unsigned short* xbf  = kws + per;

  const bool bigws  = ws_size >= (size_t)38 * 1024 * 1024;
  const bool hugews = ws_size >= (size_t)40 * 1024 * 1024;
  unsigned short* wqbf = vtws + per;                       // d_ws + 32 MB
  unsigned short* wobf = wqbf + (size_t)3 * C_ * C_;       // d_ws + 38 MB

  // Primary: single cooperative fused kernel (kills 4-5 launch gaps).
  if (bigws) {
    int dev = 0, coop = 0;
    hipGetDevice(&dev);
    hipDeviceGetAttribute(&coop, hipDeviceAttributeCooperativeLaunch, dev);
    if (coop) {
      void* args[] = {(void*)&x, (void*)&W_qkv, (void*)&b_qkv, (void*)&W_out,
                      (void*)&b_out, (void*)&out, (void*)&qws, (void*)&vtws,
                      (void*)&kws, (void*)&xbf, (void*)&wqbf};
      if (hipLaunchCooperativeKernel((void*)fused_all, dim3(512), dim3(256),
                                     args, 0, stream) == hipSuccess)
        return;
    }
  }

  // Fallback: R11 multi-dispatch path.
  if (hugews) {
    conv_tri<<<dim3(2048), 256, 0, stream>>>(
        x, xbf, (int)(per >> 3),
        W_qkv, wqbf, (3 * C_ * C_) >> 3,
        W_out, wobf, (C_ * C_) >> 3);
    gemm_bt<0, 0, 1><<<dim3(3072 / 128, 8192 / 128), 256, 0, stream>>>(
        xbf, (const void*)wqbf, b_qkv, nullptr, qws, kws, vtws);
  } else if (bigws) {
    conv_tri<<<dim3(2048), 256, 0, stream>>>(
        x, xbf, (int)(per >> 3),
        W_qkv, wqbf, (3 * C_ * C_) >> 3,
        nullptr, nullptr, 0);
    gemm_bt<0, 0, 1><<<dim3(3072 / 128, 8192 / 128), 256, 0, stream>>>(
        xbf, (const void*)wqbf, b_qkv, nullptr, qws, kws, vtws);
  } else {
    conv_bf16<<<dim3(2048), 256, 0, stream>>>(x, xbf, (int)(per >> 3));
    gemm_bt<0, 0, 0><<<dim3(3072 / 128, 8192 / 128), 256, 0, stream>>>(
        xbf, (const void*)W_qkv, b_qkv, nullptr, qws, kws, vtws);
  }

  attn_causal<<<dim3(8 * 64), 256, 0, stream>>>(qws, kws, vtws);

  if (hugews) {
    gemm_bt<1, 1, 1><<<dim3(1024 / 128, 8192 / 128), 256, 0, stream>>>(
        qws, (const void*)wobf, b_out, out, nullptr, nullptr, nullptr);
  } else {
    conv_bf16<<<dim3(512), 256, 0, stream>>>(W_out, vtws, (C_ * C_) >> 3);
    gemm_bt<1, 1, 1><<<dim3(1024 / 128, 8192 / 128), 256, 0, stream>>>(
        qws, (const void*)vtws, b_out, out, nullptr, nullptr, nullptr);
  }
}

// Round 13
// 281.192 us; speedup vs baseline: 1.7935x; 1.7935x over previous
//
#include <hip/hip_runtime.h>
#include <cstdint>
#include <cstddef>

// Problem constants
#define B_ 4
#define T_ 2048
#define C_ 1024
#define H_ 16
#define D_ 64

typedef __attribute__((ext_vector_type(8))) __bf16 bf16x8;
typedef __attribute__((ext_vector_type(4))) float floatx4;

#define QSCL (0.125f * 1.44269504088896f)  // 1/sqrt(64) * log2(e), folded into Q
#define FMAX 24.0f  // fixed softmax offset (log2 domain); scores ~N(0,0.33)

__device__ __forceinline__ unsigned short f2bf(float f) {
  union { float f; unsigned int u; } v; v.f = f;
  unsigned int r = v.u + 0x7fffu + ((v.u >> 16) & 1u);  // RNE
  return (unsigned short)(r >> 16);
}
__device__ __forceinline__ ushort4 pk4(float a, float b, float c, float d) {
  ushort4 u; u.x = f2bf(a); u.y = f2bf(b); u.z = f2bf(c); u.w = f2bf(d);
  return u;
}
__device__ __forceinline__ bf16x8 cvt8(float4 a, float4 b) {
  bf16x8 r;
  r[0] = a.x; r[1] = a.y; r[2] = a.z; r[3] = a.w;
  r[4] = b.x; r[5] = b.y; r[6] = b.z; r[7] = b.w;
  return r;
}
__device__ __forceinline__ unsigned pkbf2(float a, float b) {
  union { __bf16 h[2]; unsigned u; } w;
  w.h[0] = (__bf16)a; w.h[1] = (__bf16)b;
  return w.u;
}

// async 16B global -> LDS (dest = wave-uniform base + lane*16)
__device__ __forceinline__ void gl_lds16(const void* g, void* l) {
  __builtin_amdgcn_global_load_lds(
      (const __attribute__((address_space(1))) unsigned int*)g,
      (__attribute__((address_space(3))) unsigned int*)l, 16, 0, 0);
}

// Bulk fp32 -> bf16 (memory-bound; 16B/lane both sides)
__global__ __launch_bounds__(256)
void conv_bf16(const float* __restrict__ src, unsigned short* __restrict__ dst,
               int n8) {
  for (int i = blockIdx.x * 256 + threadIdx.x; i < n8; i += gridDim.x * 256) {
    const float4* s = (const float4*)src + 2 * (size_t)i;
    float4 a = s[0], b = s[1];
    ((bf16x8*)dst)[i] = cvt8(a, b);
  }
}

// Up to three conversions in one dispatch (kills launch gaps).
__global__ __launch_bounds__(256)
void conv_tri(const float* __restrict__ s1, unsigned short* __restrict__ d1, int n1,
              const float* __restrict__ s2, unsigned short* __restrict__ d2, int n2,
              const float* __restrict__ s3, unsigned short* __restrict__ d3, int n3) {
  for (int i = blockIdx.x * 256 + threadIdx.x; i < n1 + n2 + n3; i += gridDim.x * 256) {
    const float4* sp; bf16x8* dp;
    if (i < n1)           { sp = (const float4*)s1 + 2 * (size_t)i;       dp = (bf16x8*)d1 + i; }
    else if (i < n1 + n2) { int j = i - n1;      sp = (const float4*)s2 + 2 * (size_t)j; dp = (bf16x8*)d2 + j; }
    else                  { int j = i - n1 - n2; sp = (const float4*)s3 + 2 * (size_t)j; dp = (bf16x8*)d3 + j; }
    float4 a = sp[0], b = sp[1];
    *dp = cvt8(a, b);
  }
}

// ---------------------------------------------------------------------------
// gemm32 (R13): C = A[M,1024] @ W[N,1024]^T + bias, both operands bf16.
// 128x128 tile, 4 waves of 64x64, 16x16x32 MFMA, BK=32, FOUR LDS buffers,
// prefetch depth 3, raw s_barrier with COUNTED s_waitcnt vmcnt(8) (T3/T4).
// Mechanism: the R10 dbuf/depth-1 structure exposed (DMA_latency - compute)
// ~300cy per K-step at every barrier (both lockstep blocks stall together ->
// the ~50% no-pipe-issuing cycles).  Depth-3 gives each tile 3 compute phases
// to land; the barrier never drains vmcnt to 0 mid-loop.
// Swizzle (rule 21, both sides): chunk ^= (row>>1)&3 within the 4x16B row;
// 16 lanes/quad then cover all 8 bank-quartets exactly 2x (free 2-way).
// Buffer reuse at distance 4 is race-free: all fragment ds_reads are consumed
// by MFMAs before each barrier.
// ---------------------------------------------------------------------------
template<int EPI, int GATHER>
__global__ __launch_bounds__(256, 2)
void gemm32(const unsigned short* __restrict__ Abf,
            const unsigned short* __restrict__ Wb,
            const float* __restrict__ bias,
            float* __restrict__ out,
            unsigned short* __restrict__ qws,
            unsigned short* __restrict__ kws,
            unsigned short* __restrict__ vtws)
{
  alignas(16) __shared__ unsigned short As[4][128 * 32];  // 4 x 8KB
  alignas(16) __shared__ unsigned short Bs[4][128 * 32];  // 4 x 8KB
  const int tid  = threadIdx.x;
  const int lane = tid & 63;
  const int wid  = tid >> 6;
  const int col  = lane & 15;
  const int quad = lane >> 4;
  const int wm = (wid >> 1) << 6;
  const int wn = (wid & 1) << 6;
  const int bm = blockIdx.y << 7;
  const int bn = blockIdx.x << 7;

  floatx4 acc[4][4];
#pragma unroll
  for (int i = 0; i < 4; ++i)
#pragma unroll
    for (int j = 0; j < 4; ++j)
      acc[i][j] = (floatx4){0.f, 0.f, 0.f, 0.f};

  // Stage one 128x32 A-tile + B-tile into buffer nb (4 gl_lds16 per thread).
  // Wave w, issue q2: rows [(w*2+q2)*16, +16); lane l -> row +=(l>>2), slot l&3.
  // LDS dest linear; global source chunk = slot ^ ((row>>1)&3).
  auto stage = [&](int k0, int nb) {
#pragma unroll
    for (int q2 = 0; q2 < 2; ++q2) {
      const int rloc = (((wid << 1) | q2) << 4) + (lane >> 2);  // 0..127
      const int swc  = (lane & 3) ^ ((rloc >> 1) & 3);          // src chunk
      const char* dstA = (char*)&As[nb][0] + (((wid << 1) | q2) << 10);
      const char* dstB = (char*)&Bs[nb][0] + (((wid << 1) | q2) << 10);
      const unsigned short* ga;
      if (GATHER) {
        const int m = bm + rloc;
        const int b = m >> 11, t = m & 2047;
        const int hh = k0 >> 6;                     // D=64: 2 K-steps per head
        const int d  = (k0 & 63) + (swc << 3);
        ga = Abf + ((((size_t)(b * 16 + hh) << 11) + t) << 6) + d;
      } else {
        ga = Abf + (size_t)(bm + rloc) * 1024 + k0 + (swc << 3);
      }
      gl_lds16(ga, (void*)dstA);
      gl_lds16(Wb + (size_t)(bn + rloc) * 1024 + k0 + (swc << 3), (void*)dstB);
    }
  };

  // ---- prologue: tiles 0,1,2 in flight (12 loads/wave); wait tile 0 ----
  stage(0, 0);
  stage(32, 1);
  stage(64, 2);
  asm volatile("s_waitcnt vmcnt(8)" ::: "memory");
  __builtin_amdgcn_s_barrier();
  __builtin_amdgcn_sched_barrier(0);

  for (int kt = 0; kt < 32; ++kt) {
    const int buf = kt & 3;
    // issue DMA for tile kt+3 (3-deep; overwrites buf used at kt-1, whose
    // reads completed before the previous barrier)
    if (kt + 3 < 32) stage((kt + 3) << 5, (kt + 3) & 3);

    // ---- fragments (swizzled read) + 16 MFMA ----
    bf16x8 af[4], bfr[4];
#pragma unroll
    for (int i = 0; i < 4; ++i) {
      const int r = wm + i * 16 + col;
      af[i] = *(const bf16x8*)&As[buf][(r << 5) + ((quad ^ ((r >> 1) & 3)) << 3)];
    }
#pragma unroll
    for (int j = 0; j < 4; ++j) {
      const int r = wn + j * 16 + col;
      bfr[j] = *(const bf16x8*)&Bs[buf][(r << 5) + ((quad ^ ((r >> 1) & 3)) << 3)];
    }
    __builtin_amdgcn_s_setprio(1);
#pragma unroll
    for (int i = 0; i < 4; ++i)
#pragma unroll
      for (int j = 0; j < 4; ++j)
        acc[i][j] = __builtin_amdgcn_mfma_f32_16x16x32_bf16(af[i], bfr[j], acc[i][j], 0, 0, 0);
    __builtin_amdgcn_s_setprio(0);

    // ---- counted-vmcnt barrier: tile kt+1 resident; kt+2/kt+3 stay in
    //      flight ACROSS the barrier (drain to 0 only in the epilogue) ----
    if (kt < 29)       { asm volatile("s_waitcnt vmcnt(8)" ::: "memory"); }
    else if (kt == 29) { asm volatile("s_waitcnt vmcnt(4)" ::: "memory"); }
    else if (kt == 30) { asm volatile("s_waitcnt vmcnt(0)" ::: "memory"); }
    __builtin_amdgcn_s_barrier();
    __builtin_amdgcn_sched_barrier(0);
  }

  // Epilogue.  C/D layout: row = quad*4 + r, col = lane&15 (m89/m91).
#pragma unroll
  for (int i = 0; i < 4; ++i) {
    const int row = bm + wm + i * 16 + quad * 4;  // + r
#pragma unroll
    for (int j = 0; j < 4; ++j) {
      const int n  = bn + wn + j * 16 + col;
      const float bv = bias[n];
      float v[4];
#pragma unroll
      for (int r = 0; r < 4; ++r) v[r] = acc[i][j][r] + bv;

      if (EPI == 1) {
#pragma unroll
        for (int r = 0; r < 4; ++r)
          out[(size_t)(row + r) * 1024 + n] = v[r];
      } else {
        const int s   = n >> 10;        // 0=q 1=k 2=v
        const int rem = n & 1023;
        const int h   = rem >> 6;
        const int d   = rem & 63;
        const int b   = row >> 11;      // 128-row block never crosses a batch
        const int t   = row & 2047;
        const size_t bh = (size_t)(b * H_ + h);
        if (s == 0) {
#pragma unroll
          for (int r = 0; r < 4; ++r)
            qws[(bh * T_ + t + r) * D_ + d] = f2bf(v[r] * QSCL);
        } else if (s == 1) {
#pragma unroll
          for (int r = 0; r < 4; ++r)
            kws[(bh * T_ + t + r) * D_ + d] = f2bf(v[r]);
        } else {
          *(ushort4*)&vtws[(bh * D_ + d) * T_ + t] = pk4(v[0], v[1], v[2], v[3]);
        }
      }
    }
  }
}

// Fallback GEMM (R10 dbuf BK=64) — only used when ws < 38 MB (WBF=0 path).
template<int EPI, int GATHER, int WBF>
__global__ __launch_bounds__(256, 2)
void gemm_bt(const unsigned short* __restrict__ Abf,
             const void* __restrict__ Wraw,
             const float* __restrict__ bias,
             float* __restrict__ out,
             unsigned short* __restrict__ qws,
             unsigned short* __restrict__ kws,
             unsigned short* __restrict__ vtws)
{
  alignas(16) __shared__ unsigned short As[2][128 * 64];
  alignas(16) __shared__ unsigned short Bs[2][WBF ? 128 * 64 : 128 * 72];
  const int tid  = threadIdx.x;
  const int lane = tid & 63;
  const int wid  = tid >> 6;
  const int col  = lane & 15;
  const int quad = lane >> 4;
  const int wm = (wid >> 1) << 6;
  const int wn = (wid & 1) << 6;
  const int bm = blockIdx.y << 7;
  const int bn = blockIdx.x << 7;

  const float* Wf          = (const float*)Wraw;
  const unsigned short* Wb = (const unsigned short*)Wraw;

  const int r0 = tid >> 3;
  const int c0 = tid & 7;

  floatx4 acc[4][4];
#pragma unroll
  for (int i = 0; i < 4; ++i)
#pragma unroll
    for (int j = 0; j < 4; ++j)
      acc[i][j] = (floatx4){0.f, 0.f, 0.f, 0.f};

#define GSTAGE(k0_, nb_)                                                      \
  do {                                                                        \
    _Pragma("unroll") for (int s = 0; s < 4; ++s) {                           \
      const int row  = (s << 5) + r0;                                         \
      const int colE = ((c0 ^ (row & 7)) << 3);                               \
      const unsigned short* gsrc;                                             \
      if (GATHER) {                                                           \
        const int m = bm + row;                                               \
        const int b = m >> 11, t = m & 2047;                                  \
        const int hh = (k0_) >> 6;                                            \
        gsrc = Abf + ((((size_t)(b * 16 + hh) << 11) + t) << 6) + colE;       \
      } else {                                                                \
        gsrc = Abf + (size_t)(bm + row) * 1024 + (k0_) + colE;                \
      }                                                                       \
      gl_lds16(gsrc, (char*)&As[nb_][0] + (s << 12) + (wid << 10));           \
      if (WBF) {                                                              \
        const unsigned short* ws2 = Wb + (size_t)(bn + row) * 1024 + (k0_) + colE; \
        gl_lds16(ws2, (char*)&Bs[nb_][0] + (s << 12) + (wid << 10));          \
      } else {                                                                \
        const int kc = c0 << 3;                                               \
        const float* wsrc = &Wf[(size_t)(bn + row) * 1024 + (k0_) + kc];      \
        float4 w0 = *(const float4*)wsrc;                                     \
        float4 w1 = *(const float4*)(wsrc + 4);                               \
        *(bf16x8*)&Bs[nb_][row * 72 + kc] = cvt8(w0, w1);                     \
      }                                                                       \
    }                                                                         \
  } while (0)

  GSTAGE(0, 0);
  __syncthreads();

  for (int kt = 0; kt < 16; ++kt) {
    const int buf = kt & 1;
    if (kt + 1 < 16) GSTAGE((kt + 1) << 6, buf ^ 1);

#pragma unroll
    for (int kk = 0; kk < 64; kk += 32) {
      bf16x8 af[4], bfr[4];
#pragma unroll
      for (int i = 0; i < 4; ++i) {
        const int r = wm + i * 16 + col;
        af[i] = *(const bf16x8*)&As[buf][(r << 6) + ((kk + quad * 8) ^ ((r & 7) << 3))];
      }
#pragma unroll
      for (int j = 0; j < 4; ++j) {
        const int r = wn + j * 16 + col;
        if (WBF)
          bfr[j] = *(const bf16x8*)&Bs[buf][(r << 6) + ((kk + quad * 8) ^ ((r & 7) << 3))];
        else
          bfr[j] = *(const bf16x8*)&Bs[buf][r * 72 + kk + quad * 8];
      }
#pragma unroll
      for (int i = 0; i < 4; ++i)
#pragma unroll
        for (int j = 0; j < 4; ++j)
          acc[i][j] = __builtin_amdgcn_mfma_f32_16x16x32_bf16(af[i], bfr[j], acc[i][j], 0, 0, 0);
    }
    __syncthreads();
  }
#undef GSTAGE

#pragma unroll
  for (int i = 0; i < 4; ++i) {
    const int row = bm + wm + i * 16 + quad * 4;
#pragma unroll
    for (int j = 0; j < 4; ++j) {
      const int n  = bn + wn + j * 16 + col;
      const float bv = bias[n];
      float v[4];
#pragma unroll
      for (int r = 0; r < 4; ++r) v[r] = acc[i][j][r] + bv;

      if (EPI == 1) {
#pragma unroll
        for (int r = 0; r < 4; ++r)
          out[(size_t)(row + r) * 1024 + n] = v[r];
      } else {
        const int s   = n >> 10;
        const int rem = n & 1023;
        const int h   = rem >> 6;
        const int d   = rem & 63;
        const int b   = row >> 11;
        const int t   = row & 2047;
        const size_t bh = (size_t)(b * H_ + h);
        if (s == 0) {
#pragma unroll
          for (int r = 0; r < 4; ++r)
            qws[(bh * T_ + t + r) * D_ + d] = f2bf(v[r] * QSCL);
        } else if (s == 1) {
#pragma unroll
          for (int r = 0; r < 4; ++r)
            kws[(bh * T_ + t + r) * D_ + d] = f2bf(v[r]);
        } else {
          *(ushort4*)&vtws[(bh * D_ + d) * T_ + t] = pk4(v[0], v[1], v[2], v[3]);
        }
      }
    }
  }
}

// Flash-style causal attention v8 (R11, unchanged): 64 q-rows/wave, 256-q
// band/block, diagonal-tile skip, permlane in-reg P transpose, bare v_exp,
// -FMAX C-init, ones-MFMA l-sum, 2-buffer K/V DMA, one barrier/tile.
__global__ __launch_bounds__(256, 2)
void attn_causal(unsigned short* __restrict__ qws,
                 const unsigned short* __restrict__ kws,
                 const unsigned short* __restrict__ vtws)
{
  alignas(16) __shared__ unsigned short Ks[2][64 * 64];
  alignas(16) __shared__ unsigned short Vs[2][64 * 64];
  const int tid  = threadIdx.x;
  const int lane = tid & 63;
  const int wid  = tid >> 6;
  const int col  = lane & 15;
  const int quad = lane >> 4;

  const int bh   = blockIdx.x & 63;
  const int band = 7 - (blockIdx.x >> 6);

  const unsigned short* Kp  = kws + (size_t)bh * T_ * D_;
  const unsigned short* Vtp = vtws + (size_t)bh * D_ * T_;

  bf16x8 vones;
#pragma unroll
  for (int i = 0; i < 8; ++i) vones[i] = (__bf16)1.0f;

  const int srow8 = lane >> 3;
  const int swz   = ((lane & 7) ^ srow8) << 3;

#define STAGE(kt_, b_)                                                        \
  do {                                                                        \
    _Pragma("unroll") for (int c2 = 0; c2 < 2; ++c2) {                        \
      const int cb = wid + (c2 << 2);                                         \
      gl_lds16(Kp + ((size_t)(((kt_) << 6) + (cb << 3) + srow8) << 6) + swz,  \
               (char*)&Ks[b_][0] + (cb << 10));                               \
      gl_lds16(Vtp + ((size_t)((cb << 3) + srow8) << 11) + ((kt_) << 6) + swz,\
               (char*)&Vs[b_][0] + (cb << 10));                               \
    }                                                                         \
  } while (0)

  const int nk    = (band + 1) << 2;
  const int kdiag = (band << 2) + wid;
  const int q0    = (band << 8) + (wid << 6);
  unsigned short* Qp = qws + ((size_t)bh * T_ + q0) * D_;

  bf16x8 bq[4][2];
#pragma unroll
  for (int h = 0; h < 4; ++h) {
    bq[h][0] = *(const bf16x8*)&Qp[(h * 16 + col) * D_ + quad * 8];
    bq[h][1] = *(const bf16x8*)&Qp[(h * 16 + col) * D_ + 32 + quad * 8];
  }

  floatx4 o[4][4], ol[4];
#pragma unroll
  for (int h = 0; h < 4; ++h) {
    ol[h] = (floatx4){0.f, 0.f, 0.f, 0.f};
#pragma unroll
    for (int j = 0; j < 4; ++j) o[h][j] = (floatx4){0.f, 0.f, 0.f, 0.f};
  }

  STAGE(0, 0);
  __syncthreads();

  for (int kt = 0; kt < nk; ++kt) {
    const int buf = kt & 1;
    if (kt + 1 < nk) STAGE(kt + 1, buf ^ 1);

    if (kt <= kdiag) {
      const unsigned short* Kb = &Ks[buf][0];
      bf16x8 kA[4], kB[4];
#pragma unroll
      for (int g = 0; g < 4; ++g) {
        const int r = g * 16 + col;
        kA[g] = *(const bf16x8*)&Kb[(r << 6) + ((quad ^ (col & 7)) << 3)];
        kB[g] = *(const bf16x8*)&Kb[(r << 6) + (((quad | 4) ^ (col & 7)) << 3)];
      }
      const unsigned short* Vb = &Vs[buf][0];
      bf16x8 vA[4], vB[4];
#pragma unroll
      for (int j = 0; j < 4; ++j) {
        const int r = j * 16 + col;
        vA[j] = *(const bf16x8*)&Vb[(r << 6) + ((quad ^ (col & 7)) << 3)];
        vB[j] = *(const bf16x8*)&Vb[(r << 6) + (((quad | 4) ^ (col & 7)) << 3)];
      }

#pragma unroll
      for (int hp = 0; hp < 2; ++hp) {
        floatx4 s[2][4];
        __builtin_amdgcn_s_setprio(1);
#pragma unroll
        for (int hh = 0; hh < 2; ++hh) {
          const int h = hp * 2 + hh;
#pragma unroll
          for (int g = 0; g < 4; ++g) {
            s[hh][g] = (floatx4){-FMAX, -FMAX, -FMAX, -FMAX};
            s[hh][g] = __builtin_amdgcn_mfma_f32_16x16x32_bf16(kA[g], bq[h][0], s[hh][g], 0, 0, 0);
            s[hh][g] = __builtin_amdgcn_mfma_f32_16x16x32_bf16(kB[g], bq[h][1], s[hh][g], 0, 0, 0);
          }
        }
        __builtin_amdgcn_s_setprio(0);

        if (kt == kdiag) {
#pragma unroll
          for (int hh = 0; hh < 2; ++hh) {
            const int lim = ((hp * 2 + hh) << 4) + col;
#pragma unroll
            for (int g = 0; g < 4; ++g)
#pragma unroll
              for (int r = 0; r < 4; ++r)
                if (g * 16 + quad * 4 + r > lim) s[hh][g][r] = -1e30f;
          }
        }

#pragma unroll
        for (int hh = 0; hh < 2; ++hh)
#pragma unroll
          for (int g = 0; g < 4; ++g)
#pragma unroll
            for (int r = 0; r < 4; ++r)
              s[hh][g][r] = __builtin_amdgcn_exp2f(s[hh][g][r]);

        __builtin_amdgcn_s_setprio(1);
#pragma unroll
        for (int hh = 0; hh < 2; ++hh) {
          const int h = hp * 2 + hh;
          unsigned dw[4][2];
#pragma unroll
          for (int g = 0; g < 4; ++g) {
            dw[g][0] = pkbf2(s[hh][g][0], s[hh][g][1]);
            dw[g][1] = pkbf2(s[hh][g][2], s[hh][g][3]);
          }
          unsigned aw[4], bw[4];
          {
            auto t = __builtin_amdgcn_permlane32_swap(dw[0][0], dw[1][0], false, false);
            auto u = __builtin_amdgcn_permlane16_swap(t[0], t[1], false, false);
            aw[0] = u[0]; aw[2] = u[1];
          }
          {
            auto t = __builtin_amdgcn_permlane32_swap(dw[0][1], dw[1][1], false, false);
            auto u = __builtin_amdgcn_permlane16_swap(t[0], t[1], false, false);
            aw[1] = u[0]; aw[3] = u[1];
          }
          {
            auto t = __builtin_amdgcn_permlane32_swap(dw[2][0], dw[3][0], false, false);
            auto u = __builtin_amdgcn_permlane16_swap(t[0], t[1], false, false);
            bw[0] = u[0]; bw[2] = u[1];
          }
          {
            auto t = __builtin_amdgcn_permlane32_swap(dw[2][1], dw[3][1], false, false);
            auto u = __builtin_amdgcn_permlane16_swap(t[0], t[1], false, false);
            bw[1] = u[0]; bw[3] = u[1];
          }
          union { unsigned u[4]; bf16x8 v; } pa0, pa1;
#pragma unroll
          for (int w = 0; w < 4; ++w) { pa0.u[w] = aw[w]; pa1.u[w] = bw[w]; }

#pragma unroll
          for (int j = 0; j < 4; ++j) {
            o[h][j] = __builtin_amdgcn_mfma_f32_16x16x32_bf16(pa0.v, vA[j], o[h][j], 0, 0, 0);
            o[h][j] = __builtin_amdgcn_mfma_f32_16x16x32_bf16(pa1.v, vB[j], o[h][j], 0, 0, 0);
          }
          ol[h] = __builtin_amdgcn_mfma_f32_16x16x32_bf16(pa0.v, vones, ol[h], 0, 0, 0);
          ol[h] = __builtin_amdgcn_mfma_f32_16x16x32_bf16(pa1.v, vones, ol[h], 0, 0, 0);
        }
        __builtin_amdgcn_s_setprio(0);
      }
    }
    __syncthreads();
  }

#pragma unroll
  for (int h = 0; h < 4; ++h) {
    float lr[4];
#pragma unroll
    for (int r = 0; r < 4; ++r) lr[r] = 1.0f / ol[h][r];
#pragma unroll
    for (int j = 0; j < 4; ++j)
#pragma unroll
      for (int r = 0; r < 4; ++r)
        Qp[(size_t)(h * 16 + quad * 4 + r) * D_ + j * 16 + col] =
            f2bf(o[h][j][r] * lr[r]);
  }
#undef STAGE
}

extern "C" void kernel_launch(void* const* d_in, const int* in_sizes, int n_in,
                              void* d_out, int out_size, void* d_ws, size_t ws_size,
                              hipStream_t stream) {
  const float* x     = (const float*)d_in[0];  // [B,T,C] fp32
  const float* W_qkv = (const float*)d_in[2];  // [3C,C] fp32
  const float* b_qkv = (const float*)d_in[3];  // [3C]
  const float* W_out = (const float*)d_in[4];  // [C,C]
  const float* b_out = (const float*)d_in[5];  // [C]
  float* out = (float*)d_out;                  // [B,T,C] fp32 (32 MB)

  // Memory plan (ws scratch + d_out 32 MB as scratch):
  //   qws (Q/ctx) d_ws+0 | vtws (V^T, then W_out bf16) d_ws+16M |
  //   kws (K) d_out+0 | xbf (x bf16) d_out+16M | wqbf d_ws+32M (6MB) |
  //   wobf d_ws+38M (2MB, if ws>=40MB)
  const size_t per = (size_t)B_ * H_ * T_ * D_;  // 8M elements
  unsigned short* qws  = (unsigned short*)d_ws;
  unsigned short* vtws = qws + per;
  unsigned short* kws  = (unsigned short*)d_out;
  unsigned short* xbf  = kws + per;

  const bool bigws  = ws_size >= (size_t)38 * 1024 * 1024;
  const bool hugews = ws_size >= (size_t)40 * 1024 * 1024;
  unsigned short* wqbf = vtws + per;                       // d_ws + 32 MB
  unsigned short* wobf = wqbf + (size_t)3 * C_ * C_;       // d_ws + 38 MB

  // 0/1) fp32 -> bf16 conversions + QKV projection
  if (hugews) {
    conv_tri<<<dim3(2048), 256, 0, stream>>>(
        x, xbf, (int)(per >> 3),
        W_qkv, wqbf, (3 * C_ * C_) >> 3,
        W_out, wobf, (C_ * C_) >> 3);
    gemm32<0, 0><<<dim3(3072 / 128, 8192 / 128), 256, 0, stream>>>(
        xbf, wqbf, b_qkv, nullptr, qws, kws, vtws);
  } else if (bigws) {
    conv_tri<<<dim3(2048), 256, 0, stream>>>(
        x, xbf, (int)(per >> 3),
        W_qkv, wqbf, (3 * C_ * C_) >> 3,
        nullptr, nullptr, 0);
    gemm32<0, 0><<<dim3(3072 / 128, 8192 / 128), 256, 0, stream>>>(
        xbf, wqbf, b_qkv, nullptr, qws, kws, vtws);
  } else {
    conv_bf16<<<dim3(2048), 256, 0, stream>>>(x, xbf, (int)(per >> 3));
    gemm_bt<0, 0, 0><<<dim3(3072 / 128, 8192 / 128), 256, 0, stream>>>(
        xbf, (const void*)W_qkv, b_qkv, nullptr, qws, kws, vtws);
  }

  // 2) causal flash attention; ctx overwrites qws in [BH,T,64] layout
  attn_causal<<<dim3(8 * 64), 256, 0, stream>>>(qws, kws, vtws);

  // 3/4) output projection: both sides bf16, fp32 out
  if (hugews) {
    gemm32<1, 1><<<dim3(1024 / 128, 8192 / 128), 256, 0, stream>>>(
        qws, wobf, b_out, out, nullptr, nullptr, nullptr);
  } else if (bigws) {
    conv_bf16<<<dim3(512), 256, 0, stream>>>(W_out, vtws, (C_ * C_) >> 3);
    gemm32<1, 1><<<dim3(1024 / 128, 8192 / 128), 256, 0, stream>>>(
        qws, vtws, b_out, out, nullptr, nullptr, nullptr);
  } else {
    conv_bf16<<<dim3(512), 256, 0, stream>>>(W_out, vtws, (C_ * C_) >> 3);
    gemm_bt<1, 1, 1><<<dim3(1024 / 128, 8192 / 128), 256, 0, stream>>>(
        qws, (const void*)vtws, b_out, out, nullptr, nullptr, nullptr);
  }
}